// Round 11
// baseline (192.905 us; speedup 1.0000x reference)
//
#include <hip/hip_runtime.h>

typedef unsigned short u16;
typedef unsigned int u32;
typedef __attribute__((ext_vector_type(8))) short short8;
typedef __attribute__((ext_vector_type(4))) short s4v;
typedef __attribute__((ext_vector_type(4))) float f32x4;

#define S_LEN 2048
#define NH 16
#define HD 64
#define DM 1024
#define MSCL_C (-1.4426950408889634e9f)   /* -1e9 * log2(e) */

#if __has_builtin(__builtin_amdgcn_mfma_f32_16x16x16_bf16)
#define MFMA_K16(a, b, c) __builtin_amdgcn_mfma_f32_16x16x16_bf16(a, b, c, 0, 0, 0)
#else
#define MFMA_K16(a, b, c) __builtin_amdgcn_mfma_f32_16x16x16bf16_1k(a, b, c, 0, 0, 0)
#endif

__device__ __forceinline__ u16 f2bf(float f) {
    union { float f; u32 u; } v; v.f = f;
    u32 u = v.u;
    u32 r = u + 0x7fffu + ((u >> 16) & 1u);
    return (u16)(r >> 16);
}
__device__ __forceinline__ float bf2f(u16 h) {
    union { u32 u; float f; } v; v.u = ((u32)h) << 16;
    return v.f;
}

// packed f32->bf16 (RNE, matches f2bf) — 1 instr instead of ~10
__device__ __forceinline__ u32 cvtpk_bf16(float lo, float hi) {
    u32 r;
    asm("v_cvt_pk_bf16_f32 %0, %1, %2" : "=v"(r) : "v"(lo), "v"(hi));
    return r;
}

__device__ __forceinline__ void load_lds16(const u16* g, u16* l) {
    __builtin_amdgcn_global_load_lds((const __attribute__((address_space(1))) void*)g,
                                     (__attribute__((address_space(3))) void*)l, 16, 0, 0);
}

// ---------------- fp32 -> bf16 convert (flat) ----------------
__global__ __launch_bounds__(256) void cvt_bf16(const float* __restrict__ in, u16* __restrict__ out, int n) {
    int i = (blockIdx.x * 256 + threadIdx.x) * 4;
    if (i < n) {
        float4 v = *(const float4*)(in + i);
        ushort4 o;
        o.x = f2bf(v.x); o.y = f2bf(v.y); o.z = f2bf(v.z); o.w = f2bf(v.w);
        *(ushort4*)(out + i) = o;
    }
}

// ---------------- 4x W [K][N] fp32 -> Wt [N][K] bf16 (one launch) ----------------
__global__ __launch_bounds__(256) void transpose_w4(const float* __restrict__ W0, const float* __restrict__ W1,
                                                    const float* __restrict__ W2, const float* __restrict__ W3,
                                                    u16* __restrict__ T0, u16* __restrict__ T1,
                                                    u16* __restrict__ T2, u16* __restrict__ T3) {
    __shared__ float tile[32][33];
    int z = blockIdx.z;
    const float* W = (z == 0) ? W0 : (z == 1) ? W1 : (z == 2) ? W2 : W3;
    u16* Wt = (z == 0) ? T0 : (z == 1) ? T1 : (z == 2) ? T2 : T3;
    int tx = threadIdx.x, ty = threadIdx.y;           // 32 x 8
    int k0 = blockIdx.y * 32, n0 = blockIdx.x * 32;
    #pragma unroll
    for (int j = 0; j < 32; j += 8)
        tile[ty + j][tx] = W[(size_t)(k0 + ty + j) * DM + n0 + tx];
    __syncthreads();
    #pragma unroll
    for (int j = 0; j < 32; j += 8)
        Wt[(size_t)(n0 + ty + j) * DM + k0 + tx] = f2bf(tile[tx][ty + j]);
}

// ---------------- 128xBN GEMM, BK=64 (m97 recipe), single-buffer pipelined ----------------
// Schedule: prologue issues tile-0 loads; per iter: bar1 drains tile-k loads ->
// ds_read ALL frags into regs -> bar2 (every wave done reading LDS) -> issue tile-(k+1)
// loads into the SAME buffer -> 32 MFMAs (loads fly underneath). Same 32 KB LDS as the
// serial schedule (3 blocks/CU preserved) but the load round trip overlaps compute.
// Staging: linear LDS dest + pre-swizzled global source chunk ((lane&7)^(lane>>3));
// fragment ds_read_b128 uses chunk ((ks*4+g)^(row&7)) -> conflict-free at 128-B row stride.
// MODE 0 (NI=4): QKV fused (N=3072): Q/K RoPE fused; V head-major. MODE 1: fp32 out.
template<int MODE, int NI>   // BN = NI*32
__global__ __launch_bounds__(256) void gemm128(const u16* __restrict__ A, const u16* __restrict__ Bt,
                                               u16* __restrict__ Qh, u16* __restrict__ Kh,
                                               u16* __restrict__ Vh, float* __restrict__ Cf) {
    __shared__ u16 Al[128 * 64];
    __shared__ u16 Bl[NI * 32 * 64];
    const int K = DM;
    int tid = threadIdx.x;
    int wave = tid >> 6, lane = tid & 63, g = lane >> 4, ln = lane & 15;
    int wm = (wave >> 1) * 64, wn = (wave & 1) * (NI * 16);
    size_t mb0 = (size_t)blockIdx.y * 128, nb0 = (size_t)blockIdx.x * (NI * 32);

    f32x4 acc[4][NI];
    #pragma unroll
    for (int i = 0; i < 4; i++)
        #pragma unroll
        for (int j = 0; j < NI; j++)
            acc[i][j] = (f32x4){0.f, 0.f, 0.f, 0.f};

    int srow = lane >> 3;                   // 0..7 (row within an 8-row staging call)
    int scol = (lane & 7) ^ srow;           // pre-swizzled source chunk (rule #21)
    const u16* Ag = A + (mb0 + wave * 32 + srow) * K + scol * 8;
    u16* Alw = Al + wave * 2048;            // wave's 32 rows x 64 cols
    const u16* Bg;
    u16* Blw;
    if (NI == 4) {
        Bg = Bt + (nb0 + wave * 32 + srow) * K + scol * 8;
        Blw = Bl + wave * 2048;
    } else {
        Bg = Bt + (nb0 + wave * 16 + srow) * K + scol * 8;
        Blw = Bl + wave * 1024;
    }
    int cswz = ln & 7;

    // prologue: issue tile-0 loads
    #pragma unroll
    for (int c = 0; c < 4; c++)
        load_lds16(Ag + (size_t)(c * 8) * K, Alw + c * 512);
    #pragma unroll
    for (int c = 0; c < (NI == 4 ? 4 : 2); c++)
        load_lds16(Bg + (size_t)(c * 8) * K, Blw + c * 512);

    for (int k0 = 0; k0 < K; k0 += 64) {
        __syncthreads();   // bar1: drains tile-k loads (implicit vmcnt(0))

        short8 af[2][4], bf[2][NI];
        #pragma unroll
        for (int ks = 0; ks < 2; ks++) {
            #pragma unroll
            for (int i = 0; i < 4; i++)
                af[ks][i] = *(const short8*)&Al[(wm + i * 16 + ln) * 64 + (((ks * 4 + g) ^ cswz) * 8)];
            #pragma unroll
            for (int i = 0; i < NI; i++)
                bf[ks][i] = *(const short8*)&Bl[(wn + i * 16 + ln) * 64 + (((ks * 4 + g) ^ cswz) * 8)];
        }

        __syncthreads();   // bar2: every wave's ds_reads complete -> buffer reusable

        // issue tile-(k+1) loads; they land under this tile's MFMAs
        if (k0 + 64 < K) {
            #pragma unroll
            for (int c = 0; c < 4; c++)
                load_lds16(Ag + (size_t)(c * 8) * K + k0 + 64, Alw + c * 512);
            #pragma unroll
            for (int c = 0; c < (NI == 4 ? 4 : 2); c++)
                load_lds16(Bg + (size_t)(c * 8) * K + k0 + 64, Blw + c * 512);
        }

        #pragma unroll
        for (int ks = 0; ks < 2; ks++)
            #pragma unroll
            for (int mi = 0; mi < 4; mi++)
                #pragma unroll
                for (int ni = 0; ni < NI; ni++)
                    acc[mi][ni] = __builtin_amdgcn_mfma_f32_16x16x32_bf16(af[ks][mi], bf[ks][ni], acc[mi][ni], 0, 0, 0);
    }

    if (MODE == 1) {
        #pragma unroll
        for (int mi = 0; mi < 4; mi++)
            #pragma unroll
            for (int ni = 0; ni < NI; ni++)
                #pragma unroll
                for (int r = 0; r < 4; r++) {
                    int m = (int)mb0 + wm + mi * 16 + g * 4 + r;
                    int n = (int)nb0 + wn + ni * 16 + ln;
                    Cf[(size_t)m * DM + n] = acc[mi][ni][r];
                }
    } else {
        int nbase = (int)nb0 + wn;              // wave-uniform
        int which = nbase >> 10;
        int h = (nbase & (DM - 1)) >> 6;
        if (which < 2) {
            u16* dst = (which == 0) ? Qh : Kh;
            float inv0 = exp2f(-0.4152408746976557f * (float)ln);
            float inv1 = exp2f(-0.4152408746976557f * (float)(16 + ln));
            #pragma unroll
            for (int mi = 0; mi < 4; mi++) {
                #pragma unroll
                for (int r = 0; r < 4; r++) {
                    int m = (int)mb0 + wm + mi * 16 + g * 4 + r;
                    int b = m >> 11, s = m & (S_LEN - 1);
                    float fs = (float)s;
                    float sn0, cs0, sn1, cs1;
                    __sincosf(fs * inv0, &sn0, &cs0);
                    __sincosf(fs * inv1, &sn1, &cs1);
                    float a0 = acc[mi][0][r], a1 = acc[mi][1][r];
                    float a2 = acc[mi][2][r], a3 = acc[mi][3][r];
                    size_t base = ((size_t)(b * NH + h) * S_LEN + s) * HD;
                    dst[base + ln]      = f2bf(a0 * cs0 - a2 * sn0);
                    dst[base + 16 + ln] = f2bf(a1 * cs1 - a3 * sn1);
                    dst[base + 32 + ln] = f2bf(a0 * sn0 + a2 * cs0);
                    dst[base + 48 + ln] = f2bf(a1 * sn1 + a3 * cs1);
                }
            }
        } else {
            #pragma unroll
            for (int mi = 0; mi < 4; mi++) {
                #pragma unroll
                for (int r = 0; r < 4; r++) {
                    int m = (int)mb0 + wm + mi * 16 + g * 4 + r;
                    int b = m >> 11, s = m & (S_LEN - 1);
                    size_t base = ((size_t)(b * NH + h) * S_LEN + s) * HD;
                    #pragma unroll
                    for (int ni = 0; ni < 4; ni++)
                        Vh[base + ni * 16 + ln] = f2bf(acc[mi][ni][r]);
                }
            }
        }
    }
}

// ---------------- V transpose: [BH][S][HD] -> [BH][HD][S]; also emits Mg = (1-am)*MSCL ----------------
__global__ __launch_bounds__(256) void vtrans(const u16* __restrict__ Vh, u16* __restrict__ Vt,
                                              const float* __restrict__ amask, float* __restrict__ Mg) {
    __shared__ u16 t[64][70];
    int tid = threadIdx.x;
    int s0 = blockIdx.x * 64, bh = blockIdx.y;
    if (bh == 0) {                          // 32 blocks x 256 threads cover 2*S_LEN
        int idx = blockIdx.x * 256 + tid;
        if (idx < 2 * S_LEN) Mg[idx] = (1.0f - amask[idx]) * MSCL_C;
    }
    int r = tid >> 2, c = (tid & 3) * 8;
    const u16* src = Vh + ((size_t)bh * S_LEN + s0) * HD;
    *(short8*)&t[r][c]      = *(const short8*)(src + (size_t)r * HD + c);
    *(short8*)&t[r][c + 32] = *(const short8*)(src + (size_t)r * HD + c + 32);
    __syncthreads();
    u16* dst = Vt + ((size_t)bh * HD + r) * S_LEN + s0;
    short8 o0, o1;
    #pragma unroll
    for (int j = 0; j < 8; j++) {
        o0[j] = (short)t[c + j][r];
        o1[j] = (short)t[c + 32 + j][r];
    }
    *(short8*)(dst + c)      = o0;
    *(short8*)(dst + c + 32) = o1;
}

// ---------------- Flash attention: S^T formulation, in-register P, K-split=4 ----------------
// S^T = K*Q^T (MFMA operand swap) -> P^T C-layout == B-operand layout of 16x16x16 MFMA
// -> PV (O^T = V^T * P^T) consumes P directly from registers. No P LDS round-trip.
// K staging: global_load_lds direct (linear LDS dest = wave*512 + lane*8 u16; global
// source pre-swizzled chunk scid^s7). V reg-staged (needs 8B half-swap on row&8).
// K/V LDS: stride 64 + XOR swizzle (c ^= row&7); V additionally half-swapped on row&8
// so the b64 PV reads are fully conflict-free.
// Mask from global Mg=(1-am)*MSCL, prefetched into registers one tile ahead -> no Ml
// in LDS -> LDS EXACTLY 32768 B (residency-granule experiment: 33280 B allocated a
// 64 KB granule -> ~1.25 blocks/CU resident; 32768 should unlock 2x residency).
// Double-buffered LDS; next tile's loads issued right after the barrier (T3-lite).
// Wave-uniform skips: fully-masked tiles skipped; causal cndmask only on diagonal tiles.
// XCD-aware 1-D grid swizzle (T1): 2048 blocks = 8 xcd x 4 bh x 64 inner (bijective:
// xcd = i&7, bh = xcd*4 + ((i>>3)>>6), inner = (i>>3)&63). All 64 blocks sharing a bh
// land on one XCD -> K/V (512 KB/bh) XCD-L2-resident; longest q-blocks first per bh.
// Output O^T stored unnormalized to Op[bh][d][q]; reduce pass combines 4 splits.
__global__ __launch_bounds__(512, 4) void flash_kernel(const u16* __restrict__ Qh, const u16* __restrict__ Kh,
                                                       const u16* __restrict__ Vt, const float* __restrict__ Mg,
                                                       u16* __restrict__ Op0, u16* __restrict__ Op1,
                                                       u16* __restrict__ Op2, u16* __restrict__ Op3,
                                                       float* __restrict__ L0, float* __restrict__ L1,
                                                       float* __restrict__ L2, float* __restrict__ L3) {
    __shared__ u16 Kl[2][64 * 64];
    __shared__ u16 Vl[2][64 * 64];
    int tid = threadIdx.x;
    int wave = tid >> 6, lane = tid & 63, g = lane >> 4, ln = lane & 15;
    // XCD-aware block swizzle: 2048 = 8 xcd x 4 bh x 64 inner (ranges verified)
    int i = (int)blockIdx.x;
    int xcd = i & 7;                         // 0..7
    int j = i >> 3;                          // 0..255
    int bh = xcd * 4 + (j >> 6);             // 0..31  (4 bh per XCD)
    int inner = j & 63;                      // 0..63
    int qblk = 15 - (inner >> 2);            // longest blocks dispatched first
    int sp = inner & 3;
    int b = bh >> 4;
    int q0 = qblk * 128 + wave * 16;
    int qv = q0 + ln;
    const u16* Qb = Qh + (size_t)bh * (S_LEN * HD);
    const u16* Kb = Kh + (size_t)bh * (S_LEN * HD);
    const u16* Vb = Vt + (size_t)bh * (S_LEN * HD);
    const float* Mb = Mg + b * S_LEN;

    short8 qa0 = *(const short8*)(Qb + (size_t)(q0 + ln) * HD + g * 8);
    short8 qa1 = *(const short8*)(Qb + (size_t)(q0 + ln) * HD + 32 + g * 8);

    f32x4 O[4];
    #pragma unroll
    for (int i2 = 0; i2 < 4; i2++) O[i2] = (f32x4){0.f, 0.f, 0.f, 0.f};
    float lsum = 0.f;
    const float SCL = 0.125f * 1.4426950408889634f;       // scale * log2(e)

    int T = 2 * qblk + 2;
    // staging geometry: 512 threads; K via global_load_lds (pre-swizzled source,
    // linear dest); V via reg (1 b128 each), XOR-swizzled stride-64 LDS write
    int srow = tid >> 3, scid = tid & 7, s7 = srow & 7;
    int stoff = srow * 64 + ((scid ^ s7) * 8);
    const u16* KgL = Kb + (size_t)srow * HD + ((scid ^ s7) * 8);   // pre-swizzled source
    const u16* VgP = Vb + (size_t)srow * S_LEN + scid * 8;
    bool vswap = (wave & 1);                // == (srow & 8) != 0, wave-uniform

    // loop-invariant swizzled offsets
    int l7 = ln & 7;
    int kc0 = (g ^ l7) * 8;                 // K frag cols 0..31
    int kc1 = ((4 + g) ^ l7) * 8;           // K frag cols 32..63
    int rbq = ln * 64;                      // row base within 16-row tile
    int vcoff[4];
    #pragma unroll
    for (int n0 = 0; n0 < 4; n0++)
        vcoff[n0] = (((n0 * 2 + (g >> 1)) ^ l7) * 8) + ((((g & 1) ^ (ln >> 3)) & 1) * 4);

    // prologue: stage first tile (K direct-to-LDS, V and mask into registers)
    load_lds16(KgL + (size_t)(sp * 64) * HD, &Kl[0][wave * 512]);
    short8 vR = *(const short8*)(VgP + sp * 64);
    f32x4 mkR[4];
    #pragma unroll
    for (int n0 = 0; n0 < 4; n0++)
        mkR[n0] = *(const f32x4*)(Mb + sp * 64 + n0 * 16 + g * 4);
    int cur = 0;

    for (int kt = sp; kt < T; kt += 4) {
        int kbase = kt * 64;
        // write staged V regs into LDS[cur]; 8B halves swapped on odd waves
        short8 vS = vR;
        if (vswap) vS = __builtin_shufflevector(vR, vR, 4, 5, 6, 7, 0, 1, 2, 3);
        *(short8*)(Vl[cur] + stoff) = vS;
        __syncthreads();   // implicit vmcnt(0): K gload_lds for this tile has landed

        f32x4 mk[4];
        #pragma unroll
        for (int n0 = 0; n0 < 4; n0++) mk[n0] = mkR[n0];

        // issue next tile's loads; they land under this tile's compute
        if (kt + 4 < T) {
            load_lds16(KgL + (size_t)(kbase + 256) * HD, &Kl[cur ^ 1][wave * 512]);
            vR = *(const short8*)(VgP + (kbase + 256));
            #pragma unroll
            for (int n0 = 0; n0 < 4; n0++)
                mkR[n0] = *(const f32x4*)(Mb + kbase + 256 + n0 * 16 + g * 4);
        }

        if (kbase <= q0 + 15) {             // skip fully-masked wave-tiles (wave-uniform)
            const u16* Klc = Kl[cur];
            const u16* Vlc = Vl[cur];
            u32 pk[4][2];
            bool needmask = (kbase + 63 > q0);

            // ---- S^T = K*Q^T, exp2, pack P^T into registers ----
            if (!needmask) {                // clean path: no causal compares (wave-uniform)
                #pragma unroll
                for (int n0 = 0; n0 < 4; n0++) {
                    const u16* kr = Klc + (n0 * 16) * 64 + rbq;
                    short8 kb0 = *(const short8*)(kr + kc0);
                    short8 kb1 = *(const short8*)(kr + kc1);
                    f32x4 sv = (f32x4){0.f, 0.f, 0.f, 0.f};
                    sv = __builtin_amdgcn_mfma_f32_16x16x32_bf16(kb0, qa0, sv, 0, 0, 0);
                    sv = __builtin_amdgcn_mfma_f32_16x16x32_bf16(kb1, qa1, sv, 0, 0, 0);
                    float p[4];
                    #pragma unroll
                    for (int r = 0; r < 4; r++) {
                        p[r] = exp2f(sv[r] * SCL + mk[n0][r]);
                        lsum += p[r];
                    }
                    pk[n0][0] = cvtpk_bf16(p[0], p[1]);
                    pk[n0][1] = cvtpk_bf16(p[2], p[3]);
                }
            } else {                        // diagonal path: per-lane causal mask
                #pragma unroll
                for (int n0 = 0; n0 < 4; n0++) {
                    const u16* kr = Klc + (n0 * 16) * 64 + rbq;
                    short8 kb0 = *(const short8*)(kr + kc0);
                    short8 kb1 = *(const short8*)(kr + kc1);
                    f32x4 sv = (f32x4){0.f, 0.f, 0.f, 0.f};
                    sv = __builtin_amdgcn_mfma_f32_16x16x32_bf16(kb0, qa0, sv, 0, 0, 0);
                    sv = __builtin_amdgcn_mfma_f32_16x16x32_bf16(kb1, qa1, sv, 0, 0, 0);
                    int keyb = kbase + n0 * 16 + g * 4;
                    float p[4];
                    #pragma unroll
                    for (int r = 0; r < 4; r++) {
                        float s2 = sv[r] * SCL + mk[n0][r];
                        if (keyb + r > qv) s2 = -1.0e9f;
                        p[r] = exp2f(s2);
                        lsum += p[r];
                    }
                    pk[n0][0] = cvtpk_bf16(p[0], p[1]);
                    pk[n0][1] = cvtpk_bf16(p[2], p[3]);
                }
            }

            // ---- O^T += V^T * P^T : P straight from registers, V^T b64 frags from LDS ----
            __builtin_amdgcn_s_setprio(1);
            #pragma unroll
            for (int t = 0; t < 4; t++) {
                const u16* vr = Vlc + (t * 16) * 64 + rbq;
                #pragma unroll
                for (int n0 = 0; n0 < 4; n0++) {
                    s4v va = *(const s4v*)(vr + vcoff[n0]);
                    union { u32 u[2]; s4v v; } pb;
                    pb.u[0] = pk[n0][0];
                    pb.u[1] = pk[n0][1];
                    O[t] = MFMA_K16(va, pb.v, O[t]);
                }
            }
            __builtin_amdgcn_s_setprio(0);
        }
        cur ^= 1;
    }

    // ---- epilogue: lsum over all 4 g-groups (2 shuffles), store unnormalized O^T ----
    lsum += __shfl_xor(lsum, 16, 64);
    lsum += __shfl_xor(lsum, 32, 64);
    u16* Od = (sp == 0) ? Op0 : (sp == 1) ? Op1 : (sp == 2) ? Op2 : Op3;
    float* Ld = (sp == 0) ? L0 : (sp == 1) ? L1 : (sp == 2) ? L2 : L3;
    if (lane < 16) Ld[(size_t)bh * S_LEN + q0 + ln] = lsum;
    size_t obase = (size_t)bh * (HD * S_LEN) + q0 + ln;
    #pragma unroll
    for (int t = 0; t < 4; t++)
        #pragma unroll
        for (int r = 0; r < 4; r++)
            Od[obase + (size_t)(t * 16 + g * 4 + r) * S_LEN] = f2bf(O[t][r]);
}

// ---------------- Reduce: attn[b][q][h*64+d] = sum_sp Op[bh][d][q] / sum_sp L ----------------
__global__ __launch_bounds__(256) void flash_reduce(const u16* __restrict__ Op0, const u16* __restrict__ Op1,
                                                    const u16* __restrict__ Op2, const u16* __restrict__ Op3,
                                                    const float* __restrict__ L0, const float* __restrict__ L1,
                                                    const float* __restrict__ L2, const float* __restrict__ L3,
                                                    u16* __restrict__ attn) {
    __shared__ float t[64][65];
    int tid = threadIdx.x;
    int qt = blockIdx.x, bh = blockIdx.y;
    int b = bh >> 4, h = bh & (NH - 1);
    #pragma unroll
    for (int it = 0; it < 2; it++) {
        int idx = tid + it * 256;
        int d = idx >> 3, c = (idx & 7) * 8;
        size_t off = (size_t)bh * (HD * S_LEN) + (size_t)d * S_LEN + qt * 64 + c;
        short8 a0 = *(const short8*)(Op0 + off);
        short8 a1 = *(const short8*)(Op1 + off);
        short8 a2 = *(const short8*)(Op2 + off);
        short8 a3 = *(const short8*)(Op3 + off);
        #pragma unroll
        for (int j = 0; j < 8; j++)
            t[d][c + j] = bf2f((u16)a0[j]) + bf2f((u16)a1[j]) + bf2f((u16)a2[j]) + bf2f((u16)a3[j]);
    }
    __syncthreads();
    int qr = tid >> 2, dc = (tid & 3) * 16;
    int qg = qt * 64 + qr;
    size_t li = (size_t)bh * S_LEN + qg;
    float inv = 1.0f / (L0[li] + L1[li] + L2[li] + L3[li]);
    short8 o0, o1;
    #pragma unroll
    for (int j = 0; j < 8; j++) {
        o0[j] = (short)f2bf(t[dc + j][qr] * inv);
        o1[j] = (short)f2bf(t[dc + 8 + j][qr] * inv);
    }
    u16* dst = attn + ((size_t)b * S_LEN + qg) * DM + h * HD + dc;
    *(short8*)dst = o0;
    *(short8*)(dst + 8) = o1;
}

extern "C" void kernel_launch(void* const* d_in, const int* in_sizes, int n_in,
                              void* d_out, int out_size, void* d_ws, size_t ws_size,
                              hipStream_t stream) {
    const float* x     = (const float*)d_in[0];
    const float* amask = (const float*)d_in[1];
    const float* Wq    = (const float*)d_in[2];
    const float* Wk    = (const float*)d_in[3];
    const float* Wv    = (const float*)d_in[4];
    const float* Wo    = (const float*)d_in[5];
    float* out = (float*)d_out;
    char* ws = (char*)d_ws;

    // [0,8M):      x_bf (dead after gemm<0>) -> Op1
    // [8M,9.1M):   L0..L3 (overlaps Wqkv_t, which is dead after gemm<0>)
    // [9.4375M,9.453M): Mg (16 KB; starts exactly at end of L3, inside dead Wqkv_t)
    // [8M,14.7M):  Wqkv_t
    // [14M,16.7M): Wo_t (alive to the end)
    // [16M,24M):   Qh   [24M,32M): Kh
    // [32M,40M):   Vt (dead after flash) -> attn_final
    // [40M,48M):   Vh (dead after vtrans) -> Op0
    // Op2/Op3 in d_out (16 MB fp32, only written by final gemm).
    u16* x_bf   = (u16*)(ws);
    u16* Op1    = (u16*)(ws);
    u16* Wqkv_t = (u16*)(ws + 8388608);
    float* L0   = (float*)(ws + 8388608);
    float* L1   = (float*)(ws + 8650752);
    float* L2   = (float*)(ws + 8912896);
    float* L3   = (float*)(ws + 9175040);
    float* Mg   = (float*)(ws + 9437184);          // 16 KB, after L3, inside dead Wqkv_t
    u16* Wo_t   = (u16*)(ws + 14680064);
    u16* Qh     = (u16*)(ws + 16777216);
    u16* Kh     = (u16*)(ws + 25165824);
    u16* Vt     = (u16*)(ws + 33554432);
    u16* attnF  = (u16*)(ws + 33554432);           // over Vt, after flash
    u16* Vh     = (u16*)(ws + 41943040);
    u16* Op0    = (u16*)(ws + 41943040);           // over Vh, after vtrans
    u16* Op2    = (u16*)d_out;
    u16* Op3    = (u16*)d_out + 4194304;

    cvt_bf16<<<4096, 256, 0, stream>>>(x, x_bf, 2 * S_LEN * DM);

    transpose_w4<<<dim3(32, 32, 4), dim3(32, 8), 0, stream>>>(
        Wq, Wk, Wv, Wo, Wqkv_t, Wqkv_t + 1048576, Wqkv_t + 2097152, Wo_t);

    gemm128<0, 4><<<dim3(24, 32), 256, 0, stream>>>(x_bf, Wqkv_t, Qh, Kh, Vh, nullptr);

    vtrans<<<dim3(32, 2 * NH), 256, 0, stream>>>(Vh, Vt, amask, Mg);

    flash_kernel<<<dim3(2048), 512, 0, stream>>>(Qh, Kh, Vt, Mg,
                                                 Op0, Op1, Op2, Op3, L0, L1, L2, L3);

    flash_reduce<<<dim3(32, 2 * NH), 256, 0, stream>>>(Op0, Op1, Op2, Op3,
                                                       L0, L1, L2, L3, attnF);

    gemm128<1, 2><<<dim3(16, 32), 256, 0, stream>>>(attnF, Wo_t, nullptr, nullptr, nullptr, out);
}

// Round 12
// 188.020 us; speedup vs baseline: 1.0260x; 1.0260x over previous
//
#include <hip/hip_runtime.h>

typedef unsigned short u16;
typedef unsigned int u32;
typedef __attribute__((ext_vector_type(8))) short short8;
typedef __attribute__((ext_vector_type(4))) short s4v;
typedef __attribute__((ext_vector_type(4))) float f32x4;

#define S_LEN 2048
#define NH 16
#define HD 64
#define DM 1024

#if __has_builtin(__builtin_amdgcn_mfma_f32_16x16x16_bf16)
#define MFMA_K16(a, b, c) __builtin_amdgcn_mfma_f32_16x16x16_bf16(a, b, c, 0, 0, 0)
#else
#define MFMA_K16(a, b, c) __builtin_amdgcn_mfma_f32_16x16x16bf16_1k(a, b, c, 0, 0, 0)
#endif

__device__ __forceinline__ u16 f2bf(float f) {
    union { float f; u32 u; } v; v.f = f;
    u32 u = v.u;
    u32 r = u + 0x7fffu + ((u >> 16) & 1u);
    return (u16)(r >> 16);
}
__device__ __forceinline__ float bf2f(u16 h) {
    union { u32 u; float f; } v; v.u = ((u32)h) << 16;
    return v.f;
}

// packed f32->bf16 (RNE, matches f2bf) — 1 instr instead of ~10
__device__ __forceinline__ u32 cvtpk_bf16(float lo, float hi) {
    u32 r;
    asm("v_cvt_pk_bf16_f32 %0, %1, %2" : "=v"(r) : "v"(lo), "v"(hi));
    return r;
}

__device__ __forceinline__ void load_lds16(const u16* g, u16* l) {
    __builtin_amdgcn_global_load_lds((const __attribute__((address_space(1))) void*)g,
                                     (__attribute__((address_space(3))) void*)l, 16, 0, 0);
}

// ---------------- fp32 -> bf16 convert (flat) ----------------
__global__ __launch_bounds__(256) void cvt_bf16(const float* __restrict__ in, u16* __restrict__ out, int n) {
    int i = (blockIdx.x * 256 + threadIdx.x) * 4;
    if (i < n) {
        float4 v = *(const float4*)(in + i);
        ushort4 o;
        o.x = f2bf(v.x); o.y = f2bf(v.y); o.z = f2bf(v.z); o.w = f2bf(v.w);
        *(ushort4*)(out + i) = o;
    }
}

// ---------------- 4x W [K][N] fp32 -> Wt [N][K] bf16 (one launch) ----------------
__global__ __launch_bounds__(256) void transpose_w4(const float* __restrict__ W0, const float* __restrict__ W1,
                                                    const float* __restrict__ W2, const float* __restrict__ W3,
                                                    u16* __restrict__ T0, u16* __restrict__ T1,
                                                    u16* __restrict__ T2, u16* __restrict__ T3) {
    __shared__ float tile[32][33];
    int z = blockIdx.z;
    const float* W = (z == 0) ? W0 : (z == 1) ? W1 : (z == 2) ? W2 : W3;
    u16* Wt = (z == 0) ? T0 : (z == 1) ? T1 : (z == 2) ? T2 : T3;
    int tx = threadIdx.x, ty = threadIdx.y;           // 32 x 8
    int k0 = blockIdx.y * 32, n0 = blockIdx.x * 32;
    #pragma unroll
    for (int j = 0; j < 32; j += 8)
        tile[ty + j][tx] = W[(size_t)(k0 + ty + j) * DM + n0 + tx];
    __syncthreads();
    #pragma unroll
    for (int j = 0; j < 32; j += 8)
        Wt[(size_t)(n0 + ty + j) * DM + k0 + tx] = f2bf(tile[tx][ty + j]);
}

// ---------------- 128xBN GEMM, BK=64 (m97 recipe), single-buffer pipelined ----------------
// Schedule: prologue issues tile-0 loads; per iter: bar1 drains tile-k loads ->
// ds_read ALL frags into regs -> bar2 (every wave done reading LDS) -> issue tile-(k+1)
// loads into the SAME buffer -> 32 MFMAs (loads fly underneath). Same 32 KB LDS as the
// serial schedule (3 blocks/CU preserved) but the load round trip overlaps compute.
// Staging: linear LDS dest + pre-swizzled global source chunk ((lane&7)^(lane>>3));
// fragment ds_read_b128 uses chunk ((ks*4+g)^(row&7)) -> conflict-free at 128-B row stride.
// MODE 0 (NI=4): QKV fused (N=3072): Q/K RoPE fused; V head-major. MODE 1: fp32 out.
template<int MODE, int NI>   // BN = NI*32
__global__ __launch_bounds__(256) void gemm128(const u16* __restrict__ A, const u16* __restrict__ Bt,
                                               u16* __restrict__ Qh, u16* __restrict__ Kh,
                                               u16* __restrict__ Vh, float* __restrict__ Cf) {
    __shared__ u16 Al[128 * 64];
    __shared__ u16 Bl[NI * 32 * 64];
    const int K = DM;
    int tid = threadIdx.x;
    int wave = tid >> 6, lane = tid & 63, g = lane >> 4, ln = lane & 15;
    int wm = (wave >> 1) * 64, wn = (wave & 1) * (NI * 16);
    size_t mb0 = (size_t)blockIdx.y * 128, nb0 = (size_t)blockIdx.x * (NI * 32);

    f32x4 acc[4][NI];
    #pragma unroll
    for (int i = 0; i < 4; i++)
        #pragma unroll
        for (int j = 0; j < NI; j++)
            acc[i][j] = (f32x4){0.f, 0.f, 0.f, 0.f};

    int srow = lane >> 3;                   // 0..7 (row within an 8-row staging call)
    int scol = (lane & 7) ^ srow;           // pre-swizzled source chunk (rule #21)
    const u16* Ag = A + (mb0 + wave * 32 + srow) * K + scol * 8;
    u16* Alw = Al + wave * 2048;            // wave's 32 rows x 64 cols
    const u16* Bg;
    u16* Blw;
    if (NI == 4) {
        Bg = Bt + (nb0 + wave * 32 + srow) * K + scol * 8;
        Blw = Bl + wave * 2048;
    } else {
        Bg = Bt + (nb0 + wave * 16 + srow) * K + scol * 8;
        Blw = Bl + wave * 1024;
    }
    int cswz = ln & 7;

    // prologue: issue tile-0 loads
    #pragma unroll
    for (int c = 0; c < 4; c++)
        load_lds16(Ag + (size_t)(c * 8) * K, Alw + c * 512);
    #pragma unroll
    for (int c = 0; c < (NI == 4 ? 4 : 2); c++)
        load_lds16(Bg + (size_t)(c * 8) * K, Blw + c * 512);

    for (int k0 = 0; k0 < K; k0 += 64) {
        __syncthreads();   // bar1: drains tile-k loads (implicit vmcnt(0))

        short8 af[2][4], bf[2][NI];
        #pragma unroll
        for (int ks = 0; ks < 2; ks++) {
            #pragma unroll
            for (int i = 0; i < 4; i++)
                af[ks][i] = *(const short8*)&Al[(wm + i * 16 + ln) * 64 + (((ks * 4 + g) ^ cswz) * 8)];
            #pragma unroll
            for (int i = 0; i < NI; i++)
                bf[ks][i] = *(const short8*)&Bl[(wn + i * 16 + ln) * 64 + (((ks * 4 + g) ^ cswz) * 8)];
        }

        __syncthreads();   // bar2: every wave's ds_reads complete -> buffer reusable

        // issue tile-(k+1) loads; they land under this tile's MFMAs
        if (k0 + 64 < K) {
            #pragma unroll
            for (int c = 0; c < 4; c++)
                load_lds16(Ag + (size_t)(c * 8) * K + k0 + 64, Alw + c * 512);
            #pragma unroll
            for (int c = 0; c < (NI == 4 ? 4 : 2); c++)
                load_lds16(Bg + (size_t)(c * 8) * K + k0 + 64, Blw + c * 512);
        }

        #pragma unroll
        for (int ks = 0; ks < 2; ks++)
            #pragma unroll
            for (int mi = 0; mi < 4; mi++)
                #pragma unroll
                for (int ni = 0; ni < NI; ni++)
                    acc[mi][ni] = __builtin_amdgcn_mfma_f32_16x16x32_bf16(af[ks][mi], bf[ks][ni], acc[mi][ni], 0, 0, 0);
    }

    if (MODE == 1) {
        #pragma unroll
        for (int mi = 0; mi < 4; mi++)
            #pragma unroll
            for (int ni = 0; ni < NI; ni++)
                #pragma unroll
                for (int r = 0; r < 4; r++) {
                    int m = (int)mb0 + wm + mi * 16 + g * 4 + r;
                    int n = (int)nb0 + wn + ni * 16 + ln;
                    Cf[(size_t)m * DM + n] = acc[mi][ni][r];
                }
    } else {
        int nbase = (int)nb0 + wn;              // wave-uniform
        int which = nbase >> 10;
        int h = (nbase & (DM - 1)) >> 6;
        if (which < 2) {
            u16* dst = (which == 0) ? Qh : Kh;
            float inv0 = exp2f(-0.4152408746976557f * (float)ln);
            float inv1 = exp2f(-0.4152408746976557f * (float)(16 + ln));
            #pragma unroll
            for (int mi = 0; mi < 4; mi++) {
                #pragma unroll
                for (int r = 0; r < 4; r++) {
                    int m = (int)mb0 + wm + mi * 16 + g * 4 + r;
                    int b = m >> 11, s = m & (S_LEN - 1);
                    float fs = (float)s;
                    float sn0, cs0, sn1, cs1;
                    __sincosf(fs * inv0, &sn0, &cs0);
                    __sincosf(fs * inv1, &sn1, &cs1);
                    float a0 = acc[mi][0][r], a1 = acc[mi][1][r];
                    float a2 = acc[mi][2][r], a3 = acc[mi][3][r];
                    size_t base = ((size_t)(b * NH + h) * S_LEN + s) * HD;
                    dst[base + ln]      = f2bf(a0 * cs0 - a2 * sn0);
                    dst[base + 16 + ln] = f2bf(a1 * cs1 - a3 * sn1);
                    dst[base + 32 + ln] = f2bf(a0 * sn0 + a2 * cs0);
                    dst[base + 48 + ln] = f2bf(a1 * sn1 + a3 * cs1);
                }
            }
        } else {
            #pragma unroll
            for (int mi = 0; mi < 4; mi++) {
                #pragma unroll
                for (int r = 0; r < 4; r++) {
                    int m = (int)mb0 + wm + mi * 16 + g * 4 + r;
                    int b = m >> 11, s = m & (S_LEN - 1);
                    size_t base = ((size_t)(b * NH + h) * S_LEN + s) * HD;
                    #pragma unroll
                    for (int ni = 0; ni < 4; ni++)
                        Vh[base + ni * 16 + ln] = f2bf(acc[mi][ni][r]);
                }
            }
        }
    }
}

// ---------------- V transpose: [BH][S][HD] -> [BH][HD][S] ----------------
__global__ __launch_bounds__(256) void vtrans(const u16* __restrict__ Vh, u16* __restrict__ Vt) {
    __shared__ u16 t[64][70];
    int tid = threadIdx.x;
    int s0 = blockIdx.x * 64, bh = blockIdx.y;
    int r = tid >> 2, c = (tid & 3) * 8;
    const u16* src = Vh + ((size_t)bh * S_LEN + s0) * HD;
    *(short8*)&t[r][c]      = *(const short8*)(src + (size_t)r * HD + c);
    *(short8*)&t[r][c + 32] = *(const short8*)(src + (size_t)r * HD + c + 32);
    __syncthreads();
    u16* dst = Vt + ((size_t)bh * HD + r) * S_LEN + s0;
    short8 o0, o1;
    #pragma unroll
    for (int j = 0; j < 8; j++) {
        o0[j] = (short)t[c + j][r];
        o1[j] = (short)t[c + 32 + j][r];
    }
    *(short8*)(dst + c)      = o0;
    *(short8*)(dst + c + 32) = o1;
}

// ---------------- Flash attention: S^T formulation, in-register P, K-split=4 ----------------
// S^T = K*Q^T (MFMA operand swap) -> P^T C-layout == B-operand layout of 16x16x16 MFMA
// -> PV (O^T = V^T * P^T) consumes P directly from registers. No P LDS round-trip.
// K staging: global_load_lds direct (linear LDS dest = wave*512 + lane*8 u16; global
// source pre-swizzled chunk scid^s7). V reg-staged (needs 8B half-swap on row&8).
// K/V LDS: stride 64 + XOR swizzle (c ^= row&7); V additionally half-swapped on row&8
// so the b64 PV reads are fully conflict-free. Mask staged in LDS (Ml) — two A/Bs
// (R6, R11) showed global-mask register prefetch regresses ~7 us (divergent VMEM on
// the barrier-drain path). Double-buffered LDS; next tile's loads issued right after
// the barrier (T3-lite). Wave-uniform skips: fully-masked tiles skipped; causal
// cndmask only on diagonal tiles. Softmax row-sum via MFMA with all-ones A-operand
// (colsum of P^T in the 20%-busy matrix pipe) instead of 16 VALU adds + 2 shuffles.
// XCD-aware 1-D grid swizzle (T1): 2048 blocks = 8 xcd x 4 bh x 64 inner (bijective:
// xcd = i&7, bh = xcd*4 + ((i>>3)>>6), inner = (i>>3)&63). All 64 blocks sharing a bh
// land on one XCD -> K/V (512 KB/bh) XCD-L2-resident; longest q-blocks first per bh.
// Output O^T stored unnormalized to Op[bh][d][q]; reduce pass combines 4 splits.
__global__ __launch_bounds__(512, 4) void flash_kernel(const u16* __restrict__ Qh, const u16* __restrict__ Kh,
                                                       const u16* __restrict__ Vt, const float* __restrict__ amask,
                                                       u16* __restrict__ Op0, u16* __restrict__ Op1,
                                                       u16* __restrict__ Op2, u16* __restrict__ Op3,
                                                       float* __restrict__ L0, float* __restrict__ L1,
                                                       float* __restrict__ L2, float* __restrict__ L3) {
    __shared__ u16 Kl[2][64 * 64];
    __shared__ u16 Vl[2][64 * 64];
    __shared__ float Ml[2][64];
    int tid = threadIdx.x;
    int wave = tid >> 6, lane = tid & 63, g = lane >> 4, ln = lane & 15;
    // XCD-aware block swizzle: 2048 = 8 xcd x 4 bh x 64 inner (ranges verified)
    int i = (int)blockIdx.x;
    int xcd = i & 7;                         // 0..7
    int j = i >> 3;                          // 0..255
    int bh = xcd * 4 + (j >> 6);             // 0..31  (4 bh per XCD)
    int inner = j & 63;                      // 0..63
    int qblk = 15 - (inner >> 2);            // longest blocks dispatched first
    int sp = inner & 3;
    int b = bh >> 4;
    int q0 = qblk * 128 + wave * 16;
    int qv = q0 + ln;
    const u16* Qb = Qh + (size_t)bh * (S_LEN * HD);
    const u16* Kb = Kh + (size_t)bh * (S_LEN * HD);
    const u16* Vb = Vt + (size_t)bh * (S_LEN * HD);
    const float* am = amask + b * S_LEN;

    short8 qa0 = *(const short8*)(Qb + (size_t)(q0 + ln) * HD + g * 8);
    short8 qa1 = *(const short8*)(Qb + (size_t)(q0 + ln) * HD + 32 + g * 8);

    f32x4 O[4];
    #pragma unroll
    for (int i2 = 0; i2 < 4; i2++) O[i2] = (f32x4){0.f, 0.f, 0.f, 0.f};
    f32x4 Osum = (f32x4){0.f, 0.f, 0.f, 0.f};            // colsums of P^T via ones-MFMA
    const s4v ones = (s4v){(short)0x3F80, (short)0x3F80, (short)0x3F80, (short)0x3F80};
    const float SCL = 0.125f * 1.4426950408889634f;       // scale * log2(e)
    const float MSCL = -1.4426950408889634e9f;            // -1e9 * log2(e)

    int T = 2 * qblk + 2;
    // staging geometry: 512 threads; K via global_load_lds (pre-swizzled source,
    // linear dest); V via reg (1 b128 each), XOR-swizzled stride-64 LDS write
    int srow = tid >> 3, scid = tid & 7, s7 = srow & 7;
    int stoff = srow * 64 + ((scid ^ s7) * 8);
    const u16* KgL = Kb + (size_t)srow * HD + ((scid ^ s7) * 8);   // pre-swizzled source
    const u16* VgP = Vb + (size_t)srow * S_LEN + scid * 8;
    bool vswap = (wave & 1);                // == (srow & 8) != 0, wave-uniform

    // loop-invariant swizzled offsets
    int l7 = ln & 7;
    int kc0 = (g ^ l7) * 8;                 // K frag cols 0..31
    int kc1 = ((4 + g) ^ l7) * 8;           // K frag cols 32..63
    int rbq = ln * 64;                      // row base within 16-row tile
    int vcoff[4];
    #pragma unroll
    for (int n0 = 0; n0 < 4; n0++)
        vcoff[n0] = (((n0 * 2 + (g >> 1)) ^ l7) * 8) + ((((g & 1) ^ (ln >> 3)) & 1) * 4);

    // prologue: stage first tile (K direct-to-LDS, V/mask into registers)
    load_lds16(KgL + (size_t)(sp * 64) * HD, &Kl[0][wave * 512]);
    short8 vR = *(const short8*)(VgP + sp * 64);
    float mR = 0.f;
    if (tid < 64) mR = (1.0f - am[sp * 64 + tid]) * MSCL;
    int cur = 0;

    for (int kt = sp; kt < T; kt += 4) {
        int kbase = kt * 64;
        // write staged V regs into LDS[cur]; 8B halves swapped on odd waves
        short8 vS = vR;
        if (vswap) vS = __builtin_shufflevector(vR, vR, 4, 5, 6, 7, 0, 1, 2, 3);
        *(short8*)(Vl[cur] + stoff) = vS;
        if (tid < 64) Ml[cur][tid] = mR;
        __syncthreads();   // implicit vmcnt(0): K gload_lds for this tile has landed

        // issue next tile's loads; they land under this tile's compute
        if (kt + 4 < T) {
            load_lds16(KgL + (size_t)(kbase + 256) * HD, &Kl[cur ^ 1][wave * 512]);
            vR = *(const short8*)(VgP + (kbase + 256));
            if (tid < 64) mR = (1.0f - am[kbase + 256 + tid]) * MSCL;
        }

        if (kbase <= q0 + 15) {             // skip fully-masked wave-tiles (wave-uniform)
            const u16* Klc = Kl[cur];
            const u16* Vlc = Vl[cur];
            u32 pk[4][2];
            bool needmask = (kbase + 63 > q0);

            // ---- S^T = K*Q^T, exp2, pack P^T into registers ----
            if (!needmask) {                // clean path: no causal compares (wave-uniform)
                #pragma unroll
                for (int n0 = 0; n0 < 4; n0++) {
                    const u16* kr = Klc + (n0 * 16) * 64 + rbq;
                    short8 kb0 = *(const short8*)(kr + kc0);
                    short8 kb1 = *(const short8*)(kr + kc1);
                    f32x4 sv = (f32x4){0.f, 0.f, 0.f, 0.f};
                    sv = __builtin_amdgcn_mfma_f32_16x16x32_bf16(kb0, qa0, sv, 0, 0, 0);
                    sv = __builtin_amdgcn_mfma_f32_16x16x32_bf16(kb1, qa1, sv, 0, 0, 0);
                    f32x4 mkv = *(f32x4*)&Ml[cur][n0 * 16 + g * 4];
                    float p[4];
                    #pragma unroll
                    for (int r = 0; r < 4; r++)
                        p[r] = exp2f(sv[r] * SCL + mkv[r]);
                    pk[n0][0] = cvtpk_bf16(p[0], p[1]);
                    pk[n0][1] = cvtpk_bf16(p[2], p[3]);
                }
            } else {                        // diagonal path: per-lane causal mask
                #pragma unroll
                for (int n0 = 0; n0 < 4; n0++) {
                    const u16* kr = Klc + (n0 * 16) * 64 + rbq;
                    short8 kb0 = *(const short8*)(kr + kc0);
                    short8 kb1 = *(const short8*)(kr + kc1);
                    f32x4 sv = (f32x4){0.f, 0.f, 0.f, 0.f};
                    sv = __builtin_amdgcn_mfma_f32_16x16x32_bf16(kb0, qa0, sv, 0, 0, 0);
                    sv = __builtin_amdgcn_mfma_f32_16x16x32_bf16(kb1, qa1, sv, 0, 0, 0);
                    f32x4 mkv = *(f32x4*)&Ml[cur][n0 * 16 + g * 4];
                    int keyb = kbase + n0 * 16 + g * 4;
                    float p[4];
                    #pragma unroll
                    for (int r = 0; r < 4; r++) {
                        float s2 = sv[r] * SCL + mkv[r];
                        if (keyb + r > qv) s2 = -1.0e9f;
                        p[r] = exp2f(s2);
                    }
                    pk[n0][0] = cvtpk_bf16(p[0], p[1]);
                    pk[n0][1] = cvtpk_bf16(p[2], p[3]);
                }
            }

            // ---- O^T += V^T * P^T ; Osum += ones * P^T (row-sum on the matrix pipe) ----
            __builtin_amdgcn_s_setprio(1);
            #pragma unroll
            for (int n0 = 0; n0 < 4; n0++) {
                union { u32 u[2]; s4v v; } pb;
                pb.u[0] = pk[n0][0];
                pb.u[1] = pk[n0][1];
                Osum = MFMA_K16(ones, pb.v, Osum);
            }
            #pragma unroll
            for (int t = 0; t < 4; t++) {
                const u16* vr = Vlc + (t * 16) * 64 + rbq;
                #pragma unroll
                for (int n0 = 0; n0 < 4; n0++) {
                    s4v va = *(const s4v*)(vr + vcoff[n0]);
                    union { u32 u[2]; s4v v; } pb;
                    pb.u[0] = pk[n0][0];
                    pb.u[1] = pk[n0][1];
                    O[t] = MFMA_K16(va, pb.v, O[t]);
                }
            }
            __builtin_amdgcn_s_setprio(0);
        }
        cur ^= 1;
    }

    // ---- epilogue: Osum already holds complete per-column sums (no shuffles) ----
    u16* Od = (sp == 0) ? Op0 : (sp == 1) ? Op1 : (sp == 2) ? Op2 : Op3;
    float* Ld = (sp == 0) ? L0 : (sp == 1) ? L1 : (sp == 2) ? L2 : L3;
    if (lane < 16) Ld[(size_t)bh * S_LEN + q0 + ln] = Osum[0];
    size_t obase = (size_t)bh * (HD * S_LEN) + q0 + ln;
    #pragma unroll
    for (int t = 0; t < 4; t++)
        #pragma unroll
        for (int r = 0; r < 4; r++)
            Od[obase + (size_t)(t * 16 + g * 4 + r) * S_LEN] = f2bf(O[t][r]);
}

// ---------------- Reduce: attn[b][q][h*64+d] = sum_sp Op[bh][d][q] / sum_sp L ----------------
__global__ __launch_bounds__(256) void flash_reduce(const u16* __restrict__ Op0, const u16* __restrict__ Op1,
                                                    const u16* __restrict__ Op2, const u16* __restrict__ Op3,
                                                    const float* __restrict__ L0, const float* __restrict__ L1,
                                                    const float* __restrict__ L2, const float* __restrict__ L3,
                                                    u16* __restrict__ attn) {
    __shared__ float t[64][65];
    int tid = threadIdx.x;
    int qt = blockIdx.x, bh = blockIdx.y;
    int b = bh >> 4, h = bh & (NH - 1);
    #pragma unroll
    for (int it = 0; it < 2; it++) {
        int idx = tid + it * 256;
        int d = idx >> 3, c = (idx & 7) * 8;
        size_t off = (size_t)bh * (HD * S_LEN) + (size_t)d * S_LEN + qt * 64 + c;
        short8 a0 = *(const short8*)(Op0 + off);
        short8 a1 = *(const short8*)(Op1 + off);
        short8 a2 = *(const short8*)(Op2 + off);
        short8 a3 = *(const short8*)(Op3 + off);
        #pragma unroll
        for (int j = 0; j < 8; j++)
            t[d][c + j] = bf2f((u16)a0[j]) + bf2f((u16)a1[j]) + bf2f((u16)a2[j]) + bf2f((u16)a3[j]);
    }
    __syncthreads();
    int qr = tid >> 2, dc = (tid & 3) * 16;
    int qg = qt * 64 + qr;
    size_t li = (size_t)bh * S_LEN + qg;
    float inv = 1.0f / (L0[li] + L1[li] + L2[li] + L3[li]);
    short8 o0, o1;
    #pragma unroll
    for (int j = 0; j < 8; j++) {
        o0[j] = (short)f2bf(t[dc + j][qr] * inv);
        o1[j] = (short)f2bf(t[dc + 8 + j][qr] * inv);
    }
    u16* dst = attn + ((size_t)b * S_LEN + qg) * DM + h * HD + dc;
    *(short8*)dst = o0;
    *(short8*)(dst + 8) = o1;
}

extern "C" void kernel_launch(void* const* d_in, const int* in_sizes, int n_in,
                              void* d_out, int out_size, void* d_ws, size_t ws_size,
                              hipStream_t stream) {
    const float* x     = (const float*)d_in[0];
    const float* amask = (const float*)d_in[1];
    const float* Wq    = (const float*)d_in[2];
    const float* Wk    = (const float*)d_in[3];
    const float* Wv    = (const float*)d_in[4];
    const float* Wo    = (const float*)d_in[5];
    float* out = (float*)d_out;
    char* ws = (char*)d_ws;

    // [0,8M):      x_bf (dead after gemm<0>) -> Op1
    // [8M,9.1M):   L0..L3 (overlaps Wqkv_t, which is dead after gemm<0>)
    // [8M,14.7M):  Wqkv_t
    // [14M,16.7M): Wo_t (alive to the end)
    // [16M,24M):   Qh   [24M,32M): Kh
    // [32M,40M):   Vt (dead after flash) -> attn_final
    // [40M,48M):   Vh (dead after vtrans) -> Op0
    // Op2/Op3 in d_out (16 MB fp32, only written by final gemm).
    u16* x_bf   = (u16*)(ws);
    u16* Op1    = (u16*)(ws);
    u16* Wqkv_t = (u16*)(ws + 8388608);
    float* L0   = (float*)(ws + 8388608);
    float* L1   = (float*)(ws + 8650752);
    float* L2   = (float*)(ws + 8912896);
    float* L3   = (float*)(ws + 9175040);
    u16* Wo_t   = (u16*)(ws + 14680064);
    u16* Qh     = (u16*)(ws + 16777216);
    u16* Kh     = (u16*)(ws + 25165824);
    u16* Vt     = (u16*)(ws + 33554432);
    u16* attnF  = (u16*)(ws + 33554432);           // over Vt, after flash
    u16* Vh     = (u16*)(ws + 41943040);
    u16* Op0    = (u16*)(ws + 41943040);           // over Vh, after vtrans
    u16* Op2    = (u16*)d_out;
    u16* Op3    = (u16*)d_out + 4194304;

    cvt_bf16<<<4096, 256, 0, stream>>>(x, x_bf, 2 * S_LEN * DM);

    transpose_w4<<<dim3(32, 32, 4), dim3(32, 8), 0, stream>>>(
        Wq, Wk, Wv, Wo, Wqkv_t, Wqkv_t + 1048576, Wqkv_t + 2097152, Wo_t);

    gemm128<0, 4><<<dim3(24, 32), 256, 0, stream>>>(x_bf, Wqkv_t, Qh, Kh, Vh, nullptr);

    vtrans<<<dim3(32, 2 * NH), 256, 0, stream>>>(Vh, Vt);

    flash_kernel<<<dim3(2048), 512, 0, stream>>>(Qh, Kh, Vt, amask,
                                                 Op0, Op1, Op2, Op3, L0, L1, L2, L3);

    flash_reduce<<<dim3(32, 2 * NH), 256, 0, stream>>>(Op0, Op1, Op2, Op3,
                                                       L0, L1, L2, L3, attnF);

    gemm128<1, 2><<<dim3(16, 32), 256, 0, stream>>>(attnF, Wo_t, nullptr, nullptr, nullptr, out);
}